// Round 1
// 306.264 us; speedup vs baseline: 1.4447x; 1.4447x over previous
//
#include <hip/hip_runtime.h>

// VQ-VAE nearest-code lookup: MFMA filter (code-granular) + coalesced fp32 refine.
// N=65536 tokens, K=1024 codes, D=256, fp32 in/out.
// out layout (flat f32): values[N*256] | indices[N] (as float) | vectors[N*256]
//
// prep : weight -> bf16 (RTNE), sqr[k] fp32, zero worklist counter
// pass1: R5: block-shared double-buffered LDS staging of B tiles (fixes R4's
//        latency-serialized per-wave L2 gathers: 2485 cy/tile, MfmaUtil 10%).
//        Structure = m97/T3-minimum: STAGE(t+1) via global_load_lds(16B) ->
//        compute tile t from LDS -> __syncthreads. B tile is XOR-swizzled on
//        the GLOBAL source (global_load_lds writes linearly) and the same XOR
//        is applied on ds_read_b128 -> conflict-free (8 lanes per 4-bank grp).
//        sqr[] lives in LDS so the compute loop has zero VMEM ops.
//        phase A: per-row min (registers only). phase B: recompute, emit codes
//        with s <= rmin+MARGIN into LDS list, ONE global atomicAdd per block.
// pass2: quarter-wave (16 lanes) per candidate: exact fp32 dot, coalesced;
//        lexicographic (score,idx) u64 atomicMin == np.argmin tie-break.
// pass3: gather weight[idx] -> values & vectors, write indices.
//
// Margin proof: |approx-exact| per score <= 2*2^-9*2*sum|a_i b_i| ~ 1.3 typ,
// <2.5 tail; candidate test needs MARGIN >= 2*err ~ 5; MARGIN=12 -> 2.4x slack.

constexpr int N_TOK = 65536;
constexpr int KC    = 1024;
constexpr int D     = 256;

constexpr size_t IDX_OFF = (size_t)N_TOK * D;   // 16777216 floats
constexpr size_t VEC_OFF = IDX_OFF + N_TOK;     // 16842752 floats
constexpr int    WL_CAP  = 16777216;            // worklist slots in values region

#define MARGIN 12.0f

typedef __attribute__((ext_vector_type(8))) short bf16x8;
typedef __attribute__((ext_vector_type(4))) float f32x4;

__device__ inline unsigned short f2bf(float x) {
    unsigned int u = __float_as_uint(x);
    unsigned int r = (u + 0x7FFFu + ((u >> 16) & 1u)) >> 16;
    return (unsigned short)r;
}

__device__ inline unsigned int fkey(float f) {
    unsigned int b = __float_as_uint(f);
    return (b & 0x80000000u) ? ~b : (b | 0x80000000u);
}

// ---------------- prep: weight -> bf16, sqr, zero counter ----------------
__global__ __launch_bounds__(64)
void vq_prep(const float* __restrict__ w, unsigned short* __restrict__ wbf,
             float* __restrict__ sqr, int* __restrict__ cnt) {
    const int code = blockIdx.x;
    const int lane = threadIdx.x;
    float4 v = ((const float4*)w)[(size_t)code * 64 + lane];
    float s = v.x * v.x + v.y * v.y + v.z * v.z + v.w * v.w;
#pragma unroll
    for (int off = 32; off >= 1; off >>= 1) s += __shfl_xor(s, off, 64);
    unsigned short* d = wbf + (size_t)code * D + lane * 4;
    d[0] = f2bf(v.x); d[1] = f2bf(v.y); d[2] = f2bf(v.z); d[3] = f2bf(v.w);
    if (lane == 0) sqr[code] = s;
    if (code == 0 && lane == 0) *cnt = 0;
}

// ---------------- pass1: MFMA filter, LDS-staged B, two-phase ----------------
constexpr int CT   = 32;        // codes per stage (16 KB per buffer)
constexpr int NS   = KC / CT;   // 32 stages per phase
constexpr int LCAP = 3072;

struct __align__(16) P1Shared {
    unsigned short sbuf[2][CT * D];  // 32 KB double-buffered B tiles (swizzled)
    float sqr[KC];                   // 4 KB
    int   list[LCAP];                // 12 KB
    int   lcnt, gbase;
};                                   // ~48.1 KB -> >=2 blocks/CU

// Stage CT codes of wbf into dstbuf. Linear LDS dest (global_load_lds rule),
// source chunk index XOR-swizzled by (code&7) so the b128 reads are
// bank-conflict-free. 256 thr x 4 rounds x 16B = 16 KB.
__device__ __forceinline__ void stage32(const unsigned short* __restrict__ wbf,
                                        unsigned short* dstbuf, int s, int tid) {
#pragma unroll
    for (int r = 0; r < 4; ++r) {
        const int dchunk = tid + r * 256;      // 16B-chunk index 0..1023
        const int cc     = dchunk >> 5;        // local code 0..31
        const int ch     = dchunk & 31;        // chunk within code row
        const unsigned short* src =
            wbf + (((size_t)(s * CT + cc)) << 8) + ((ch ^ (cc & 7)) << 3);
        unsigned short* dst = dstbuf + (dchunk << 3);
        __builtin_amdgcn_global_load_lds(
            (const __attribute__((address_space(1))) void*)src,
            (__attribute__((address_space(3))) void*)dst, 16, 0, 0);
    }
}

template<bool EMIT>
__device__ __forceinline__ void scan(const unsigned short* __restrict__ wbf,
                                     P1Shared& sh,
                                     const bf16x8 (&a)[2][8],
                                     float (&rmin)[2][4],
                                     int row_base, int tid, int lane, int col, int quad,
                                     int* __restrict__ wl, int* __restrict__ cnt) {
    stage32(wbf, sh.sbuf[0], 0, tid);
    __syncthreads();   // also covers sqr/lcnt init on the first call
    for (int s = 0; s < NS; ++s) {
        if (s + 1 < NS) stage32(wbf, sh.sbuf[(s + 1) & 1], s + 1, tid);
        const unsigned short* sb = sh.sbuf[s & 1];
#pragma unroll
        for (int tt = 0; tt < 2; ++tt) {
            const int ccl = tt * 16 + col;        // local code in stage
            const int c0  = s * CT + tt * 16;     // global tile base code
            bf16x8 b[8];
#pragma unroll
            for (int kt = 0; kt < 8; ++kt) {
                const int ch = (quad + 4 * kt) ^ (ccl & 7);   // de-swizzle
                b[kt] = *(const bf16x8*)(sb + ccl * 256 + ch * 8);
            }
            const float sq = sh.sqr[c0 + col];
#pragma unroll
            for (int rt = 0; rt < 2; ++rt) {
                f32x4 acc = {0.f, 0.f, 0.f, 0.f};
#pragma unroll
                for (int kt = 0; kt < 8; ++kt)
                    acc = __builtin_amdgcn_mfma_f32_16x16x32_bf16(a[rt][kt], b[kt], acc, 0, 0, 0);
                if (!EMIT) {
#pragma unroll
                    for (int rg = 0; rg < 4; ++rg)
                        rmin[rt][rg] = fminf(rmin[rt][rg], sq - 2.0f * acc[rg]);
                } else {
#pragma unroll
                    for (int rg = 0; rg < 4; ++rg) {
                        const float sc = sq - 2.0f * acc[rg];
                        const bool flag = (sc <= rmin[rt][rg] + MARGIN);
                        unsigned long long mask = __ballot(flag);
                        if (mask) {
                            const int leader = __builtin_ctzll(mask);
                            const int nact   = __popcll(mask);
                            const int prefix = __popcll(mask & ((1ULL << lane) - 1ULL));
                            int wbase = 0;
                            if (lane == leader) wbase = atomicAdd(&sh.lcnt, nact);
                            wbase = __shfl(wbase, leader, 64);
                            if (flag) {
                                const int row  = row_base + rt * 16 + quad * 4 + rg;
                                const int item = (row << 10) | (c0 + col);
                                const int pos  = wbase + prefix;
                                if (pos < LCAP) {
                                    sh.list[pos] = item;
                                } else {          // rare overflow fallback
                                    int g = atomicAdd(cnt, 1);
                                    if (g < WL_CAP) wl[g] = item;
                                }
                            }
                        }
                    }
                }
            }
        }
        __syncthreads();   // stage s+1 landed; all waves done reading buf s
    }
}

// 512 blocks x 256 thr; wave handles 32 rows (2 row-tiles), all 1024 codes.
__global__ __launch_bounds__(256)
void vq_pass1(const float* __restrict__ input, const unsigned short* __restrict__ wbf,
              const float* __restrict__ sqr, int* __restrict__ wl,
              int* __restrict__ cnt, unsigned long long* __restrict__ cand) {
    __shared__ P1Shared sh;

    const int tid  = threadIdx.x;
    const int wave = tid >> 6;
    const int lane = tid & 63;
    const int col  = lane & 15;
    const int quad = lane >> 4;
    const int row_base = blockIdx.x * 128 + wave * 32;

    if (tid == 0) sh.lcnt = 0;
    ((float4*)sh.sqr)[tid] = ((const float4*)sqr)[tid];   // 1024 f32 -> LDS
    if (lane < 32) cand[row_base + lane] = 0xFFFFFFFFFFFFFFFFULL;

    // A fragments: 2 row-tiles x 8 k-tiles, bf16x8 each (32 VGPRs)
    bf16x8 a[2][8];
#pragma unroll
    for (int rt = 0; rt < 2; ++rt) {
        const float* ar = input + (size_t)(row_base + rt * 16 + col) * D;
#pragma unroll
        for (int kt = 0; kt < 8; ++kt) {
            const int k0 = kt * 32 + quad * 8;
            float4 f0 = *(const float4*)(ar + k0);
            float4 f1 = *(const float4*)(ar + k0 + 4);
            bf16x8 v;
            v[0] = (short)f2bf(f0.x); v[1] = (short)f2bf(f0.y);
            v[2] = (short)f2bf(f0.z); v[3] = (short)f2bf(f0.w);
            v[4] = (short)f2bf(f1.x); v[5] = (short)f2bf(f1.y);
            v[6] = (short)f2bf(f1.z); v[7] = (short)f2bf(f1.w);
            a[rt][kt] = v;
        }
    }

    // ---- phase A: per-row min over all 1024 codes ----
    float rmin[2][4];
#pragma unroll
    for (int rt = 0; rt < 2; ++rt)
#pragma unroll
        for (int rg = 0; rg < 4; ++rg) rmin[rt][rg] = 3.4e38f;

    scan<false>(wbf, sh, a, rmin, row_base, tid, lane, col, quad, wl, cnt);

    // butterfly min over the 16 col-lanes (xor 1,2,4,8 stays within quad)
#pragma unroll
    for (int off = 1; off <= 8; off <<= 1)
#pragma unroll
        for (int rt = 0; rt < 2; ++rt)
#pragma unroll
            for (int rg = 0; rg < 4; ++rg)
                rmin[rt][rg] = fminf(rmin[rt][rg], __shfl_xor(rmin[rt][rg], off, 64));

    // ---- phase B: recompute, emit candidates via LDS aggregation ----
    scan<true>(wbf, sh, a, rmin, row_base, tid, lane, col, quad, wl, cnt);

    // ---- flush: one global reservation per block ----
    __syncthreads();
    const int n = min(sh.lcnt, LCAP);
    if (tid == 0) sh.gbase = atomicAdd(cnt, n);
    __syncthreads();
    const int base = sh.gbase;
    for (int i = tid; i < n; i += 256) wl[base + i] = sh.list[i];
}

// ---------------- pass2: coalesced exact fp32 refine (16 lanes/cand) ------
__global__ __launch_bounds__(256)
void vq_pass2(const float* __restrict__ input, const float* __restrict__ weight,
              const float* __restrict__ sqr, const int* __restrict__ wl,
              const int* __restrict__ cnt, unsigned long long* __restrict__ cand) {
    const int sw  = threadIdx.x >> 4;       // 16 sub-waves per block
    const int sl  = threadIdx.x & 15;
    const int gsw = blockIdx.x * 16 + sw;
    const int nsw = gridDim.x * 16;
    const int n   = min(*cnt, WL_CAP);
    const float4* in4 = (const float4*)input;
    const float4* w4  = (const float4*)weight;

    for (int e = gsw; e < n; e += nsw) {
        const int ent  = wl[e];             // sub-wave-uniform (broadcast)
        const int row  = ent >> 10;
        const int code = ent & 1023;
        const float4* zr = in4 + (size_t)row * 64;
        const float4* wr = w4 + (size_t)code * 64;
        float s = 0.f;
#pragma unroll
        for (int j = 0; j < 4; ++j) {       // lane sl covers q = sl + 16*j
            float4 za = zr[sl + 16 * j];
            float4 wa = wr[sl + 16 * j];
            s = fmaf(za.x, wa.x, s);
            s = fmaf(za.y, wa.y, s);
            s = fmaf(za.z, wa.z, s);
            s = fmaf(za.w, wa.w, s);
        }
#pragma unroll
        for (int off = 1; off <= 8; off <<= 1) s += __shfl_xor(s, off, 16);
        if (sl == 0) {
            const float score = sqr[code] - 2.0f * s;
            unsigned long long key =
                ((unsigned long long)fkey(score) << 32) | (unsigned int)code;
            atomicMin(&cand[row], key);
        }
    }
}

// ---------------- pass3: gather + write outputs ----------------
__global__ __launch_bounds__(256)
void vq_pass3(const float* __restrict__ weight,
              const unsigned long long* __restrict__ cand,
              float* __restrict__ out) {
    __shared__ int fin[64];
    const int tid  = threadIdx.x;
    const int row0 = blockIdx.x * 64;
    if (tid < 64) {
        int idx = (int)(unsigned int)(cand[row0 + tid] & 0xFFFFFFFFULL);
        fin[tid] = idx;
        out[IDX_OFF + row0 + tid] = (float)idx;
    }
    __syncthreads();
    const float4* w4 = (const float4*)weight;
    float4* out4 = (float4*)out;
#pragma unroll
    for (int k = 0; k < 16; ++k) {
        int i = tid + k * 256;
        int r = i >> 6, q = i & 63;
        float4 v = w4[(size_t)fin[r] * 64 + q];
        size_t o = (size_t)(row0 + r) * 64 + q;
        out4[o] = v;                    // values
        out4[VEC_OFF / 4 + o] = v;      // vectors
    }
}

extern "C" void kernel_launch(void* const* d_in, const int* in_sizes, int n_in,
                              void* d_out, int out_size, void* d_ws, size_t ws_size,
                              hipStream_t stream) {
    const float* input  = (const float*)d_in[0];   // [64,32,32,256] f32
    const float* weight = (const float*)d_in[1];   // [1024,256] f32
    float* out = (float*)d_out;

    // ws layout (~1.04 MB)
    unsigned short* wbf = (unsigned short*)d_ws;                            // 512 KB
    float* sqr = (float*)((char*)d_ws + 524288);                            // 4 KB
    int*   cnt = (int*)((char*)d_ws + 528384);                              // 4 B
    unsigned long long* cand = (unsigned long long*)((char*)d_ws + 532480); // 512 KB

    // worklist lives in out's values region (16.7M ints); pass3 overwrites it
    int* wl = (int*)out;

    vq_prep <<<KC, 64, 0, stream>>>(weight, wbf, sqr, cnt);
    vq_pass1<<<N_TOK / 128, 256, 0, stream>>>(input, wbf, sqr, wl, cnt, cand);
    vq_pass2<<<1024, 256, 0, stream>>>(input, weight, sqr, wl, cnt, cand);
    vq_pass3<<<N_TOK / 64, 256, 0, stream>>>(weight, cand, out);
}